// Round 14
// baseline (190.733 us; speedup 1.0000x reference)
//
#include <hip/hip_runtime.h>
#include <cmath>

namespace {

constexpr int HEADS = 8;
constexpr int Bn = 4;
constexpr int Tn = 2048;
constexpr int Dn = 128;
// Q pre-scale: 128^(-1/2) * log2(e)  (whole QK scale folded into Q, exp -> exp2)
constexpr float Q_PRESCALE = 0.1275174340f;

typedef _Float16 half8 __attribute__((ext_vector_type(8)));
typedef _Float16 half4 __attribute__((ext_vector_type(4)));
typedef _Float16 half2v __attribute__((ext_vector_type(2)));
typedef float f32x4 __attribute__((ext_vector_type(4)));
typedef float f32x16 __attribute__((ext_vector_type(16)));
typedef unsigned int u32;
typedef unsigned int u32x4 __attribute__((ext_vector_type(4)));

// ---------------- cast inputs to fp16 ----------------
// (R10 lesson: fusing the cast into proj/outproj regressed ~+30us — f32 operand streams
// double L2/L3 traffic. Keep the separate cast kernel.)
__global__ __launch_bounds__(256) void cast_kernel(
    const float* __restrict__ x, const float* __restrict__ Wq, const float* __restrict__ Wk,
    const float* __restrict__ Wv, const float* __restrict__ Wu, _Float16* __restrict__ xh,
    _Float16* __restrict__ WH) {
  const int idx = blockIdx.x * 256 + threadIdx.x;
  const size_t base = (size_t)idx * 8;
  const float* src;
  _Float16* dst;
  if (base < 1048576) {
    src = x + base;
    dst = xh + base;
  } else {
    const size_t r = base - 1048576;
    const int s = (int)(r >> 17);
    src = ((s == 0) ? Wq : (s == 1) ? Wk : (s == 2) ? Wv : Wu) + (r & 131071);
    dst = WH + r;
  }
  const float4 a = *reinterpret_cast<const float4*>(src);
  const float4 b = *reinterpret_cast<const float4*>(src + 4);
  half8 h;
  h[0] = (_Float16)a.x; h[1] = (_Float16)a.y; h[2] = (_Float16)a.z; h[3] = (_Float16)a.w;
  h[4] = (_Float16)b.x; h[5] = (_Float16)b.y; h[6] = (_Float16)b.z; h[7] = (_Float16)b.w;
  *reinterpret_cast<half8*>(dst) = h;
}

// ---------------- QKV projection, fp16 MFMA ----------------
// Qh gets Q_PRESCALE folded (so flash S-MFMA output is s*log2e); Kh/Vt unscaled.
__global__ __launch_bounds__(256, 4) void proj_kernel(const _Float16* __restrict__ xh,
                                                      const _Float16* __restrict__ WH,
                                                      _Float16* __restrict__ Qh,
                                                      _Float16* __restrict__ Kh,
                                                      _Float16* __restrict__ Vt) {
  __shared__ _Float16 sB[128 * 136];
  const int tid = threadIdx.x;
  const int w = tid >> 6, lane = tid & 63, quad = lane >> 4, l16 = lane & 15;
  const int m0 = blockIdx.x * 128;
  const int n0 = blockIdx.y * 128;

#pragma unroll
  for (int it = 0; it < 8; ++it) {
    const int fid = tid + it * 256;
    const int r = fid >> 4, g = fid & 15;
    const half8 v = *reinterpret_cast<const half8*>(WH + (size_t)(n0 + r) * 128 + g * 8);
    const int p = g ^ (r & 15);
    *reinterpret_cast<half8*>(sB + r * 128 + p * 8) = v;
  }

  half8 af[2][4];
  const _Float16* xp = xh + (size_t)(m0 + w * 32 + l16) * 128 + quad * 8;
#pragma unroll
  for (int mt = 0; mt < 2; ++mt)
#pragma unroll
    for (int kk = 0; kk < 4; ++kk)
      af[mt][kk] = *reinterpret_cast<const half8*>(xp + mt * 16 * 128 + kk * 32);

  __syncthreads();

  f32x4 acc[2][8];
#pragma unroll
  for (int mt = 0; mt < 2; ++mt)
#pragma unroll
    for (int nt = 0; nt < 8; ++nt) acc[mt][nt] = (f32x4){0.f, 0.f, 0.f, 0.f};

#pragma unroll
  for (int kk = 0; kk < 4; ++kk)
#pragma unroll
    for (int nt = 0; nt < 8; ++nt) {
      const int r = nt * 16 + l16;
      const int p = (kk * 4 + quad) ^ l16;
      const half8 bf = *reinterpret_cast<const half8*>(sB + r * 128 + p * 8);
      acc[0][nt] = __builtin_amdgcn_mfma_f32_16x16x32_f16(af[0][kk], bf, acc[0][nt], 0, 0, 0);
      acc[1][nt] = __builtin_amdgcn_mfma_f32_16x16x32_f16(af[1][kk], bf, acc[1][nt], 0, 0, 0);
    }

  const int sel = n0 >> 10;
  const int h = (n0 >> 7) & 7;
  const int b = m0 >> 11;
  const int t0b = m0 & 2047;
  const int bh = b * HEADS + h;
  const float scale = (sel == 0) ? Q_PRESCALE : 1.0f;

  __syncthreads();

  if (sel < 2) {
#pragma unroll
    for (int mt = 0; mt < 2; ++mt)
#pragma unroll
      for (int nt = 0; nt < 8; ++nt)
#pragma unroll
        for (int r = 0; r < 4; ++r)
          sB[(w * 32 + mt * 16 + quad * 4 + r) * 136 + nt * 16 + l16] =
              (_Float16)(acc[mt][nt][r] * scale);
  } else {
#pragma unroll
    for (int mt = 0; mt < 2; ++mt)
#pragma unroll
      for (int nt = 0; nt < 8; ++nt)
#pragma unroll
        for (int r = 0; r < 4; ++r)
          sB[(nt * 16 + l16) * 136 + w * 32 + mt * 16 + quad * 4 + r] = (_Float16)acc[mt][nt][r];
  }
  __syncthreads();

  _Float16* dstbase;
  size_t rstride;
  if (sel == 0) {
    dstbase = Qh + ((size_t)bh * Tn + t0b) * Dn;
    rstride = Dn;
  } else if (sel == 1) {
    dstbase = Kh + ((size_t)bh * Tn + t0b) * Dn;
    rstride = Dn;
  } else {
    dstbase = Vt + ((size_t)bh * Dn) * Tn + t0b;
    rstride = Tn;
  }
#pragma unroll
  for (int it = 0; it < 8; ++it) {
    const int fid = tid + it * 256;
    const int r = fid >> 4, g = fid & 15;
    const half8 v = *reinterpret_cast<const half8*>(sB + r * 136 + g * 8);
    *reinterpret_cast<half8*>(dstbase + (size_t)r * rstride + g * 8) = v;
  }
}

// ---------------- fp16 MFMA flash attention: 128-key tiles, 1 barrier/step ----------------
// R12 post-mortem: the KT=128 single-barrier structure SPILLED (WRITE_SIZE 16.4->43.4MB
// = scratch traffic; MfmaUtil 26.7): computing all 4 sacc quadrants before consuming any
// put sacc(64) + o(64) = 128 acc-regs live -> over the 2-waves/SIMD budget.
// R13 fix (one variable): PER-KB FUSION — compute one sacc quadrant (8 S-MFMAs), softmax
// it, run its 8 PV-MFMAs, then next kb. Live accs: o(64) + sacc(16) = 80. DS traffic
// byte-identical. Everything else unchanged from R12: KT=128, 16 steps, one barrier/step
// (barrier -> stage t+1 -> prefetch t+2 -> compute t), K+V double-buffered (race audit:
// buf[nxt] writes R_t vs reads R_{t+1} and buf[cur] re-writes R_{t+1} vs reads R_t are
// both separated by barrier(t+1)), XCD remap, setprio. LDS 128KB, 1 block/CU.
__global__ __launch_bounds__(512, 2) void flash_kernel(const _Float16* __restrict__ Qh,
                                                       const _Float16* __restrict__ Kh,
                                                       const _Float16* __restrict__ Vt,
                                                       _Float16* __restrict__ Obh) {
  __shared__ _Float16 sAll[65536];
  // kbuf b: sAll + b*16384          [kcol 128][d 128], group p = g ^ (kcol&15)
  // vbuf b: sAll + 32768 + b*16384  [d 128][col 128],  group p = G ^ ((d&7)^((d>>1)&4)),
  //         storage col s holds key t = swapbits23(s) within each 16-block

  const int tid = threadIdx.x;
  const int w = tid >> 6;      // 0..7
  const int lane = tid & 63;
  const int l31 = lane & 31;
  const int h = lane >> 5;     // lane half
  // XCD-aware remap (bijective over 256 blocks): xcd = lid&7 owns bh in [4*xcd, 4*xcd+4).
  const int lid = blockIdx.x + 8 * blockIdx.y;  // 0..255
  const int xcd = lid & 7, j = lid >> 3;        // j 0..31
  const int bh = xcd * 4 + (j >> 3);            // 0..31
  const int qt = j & 7;                         // 0..7
  constexpr int KT = 128;
  constexpr int NT = Tn / KT;  // 16 steps

  // Q fragments (B-operand, 32x32x16): lane holds Q[q = qt*256 + w*32 + l31][ds*16+h*8+e]
  half8 qf[8];
  {
    const _Float16* Qp = Qh + ((size_t)bh * Tn + qt * 256 + w * 32 + l31) * Dn + h * 8;
#pragma unroll
    for (int ds = 0; ds < 8; ++ds) qf[ds] = *reinterpret_cast<const half8*>(Qp + ds * 16);
  }

  const _Float16* Kp = Kh + (size_t)bh * Tn * Dn;
  const _Float16* Vp = Vt + (size_t)bh * Dn * Tn;

  // O^T accumulators: o[db], D[row = d][col = q] (32x32 C-layout)
  f32x16 o[4];
#pragma unroll
  for (int db = 0; db < 4; ++db) o[db] = (f32x16)(0.f);
  float lsum = 0.f;

  // staging (512 threads, 128-key tile = 32KB each for K and V; 4 half8 per thread each)
  half8 kreg[4], vreg[4];
  const int kr = tid >> 4, kg = tid & 15;   // K: rows kr + it*32 (kcol), col group kg
  const int vd = tid >> 4, cg = tid & 15;   // V: rows vd + it*32 (d), col group cg
  // V column-permute (bit2<->3 of key idx within 16): store groups vG^sw / (vG|1)^sw
  const int vG = (cg >> 1) * 2;
  const int vO = (cg & 1) * 4;

  auto stageK = [&](_Float16* sK) {
#pragma unroll
    for (int it = 0; it < 4; ++it) {
      const int r = kr + it * 32;
      const int p = kg ^ (r & 15);
      *reinterpret_cast<half8*>(sK + r * 128 + p * 8) = kreg[it];
    }
  };
  auto stageV = [&](_Float16* sV) {
#pragma unroll
    for (int it = 0; it < 4; ++it) {
      const int d = vd + it * 32;
      const int sw = (d & 7) ^ ((d >> 1) & 4);
      const half8 v = vreg[it];
      half4 lo, hi;
      lo[0] = v[0]; lo[1] = v[1]; lo[2] = v[2]; lo[3] = v[3];
      hi[0] = v[4]; hi[1] = v[5]; hi[2] = v[6]; hi[3] = v[7];
      *reinterpret_cast<half4*>(sV + d * 128 + ((vG ^ sw) * 8) + vO) = lo;
      *reinterpret_cast<half4*>(sV + d * 128 + (((vG | 1) ^ sw) * 8) + vO) = hi;
    }
  };
  auto loadTile = [&](int tile) {
    const _Float16* kp = Kp + (size_t)tile * KT * Dn;
    const _Float16* vp = Vp + tile * KT;
#pragma unroll
    for (int it = 0; it < 4; ++it) {
      kreg[it] = *reinterpret_cast<const half8*>(kp + (size_t)(kr + it * 32) * Dn + kg * 8);
      vreg[it] = *reinterpret_cast<const half8*>(vp + (size_t)(vd + it * 32) * Tn + cg * 8);
    }
  };

  // ---- prologue: tile 0 -> buf0 (own-data writes, no barrier needed), tile 1 -> regs ----
  loadTile(0);
  stageK(sAll);
  stageV(sAll + 32768);
  loadTile(1);

  // ---- main loop: 16 steps, one barrier each ----
  for (int t = 0; t < NT; ++t) {
    _Float16* sKc = sAll + (t & 1) * 16384;
    _Float16* sKn = sAll + ((t + 1) & 1) * 16384;
    _Float16* sVc = sAll + 32768 + (t & 1) * 16384;
    _Float16* sVn = sAll + 32768 + ((t + 1) & 1) * 16384;

    __syncthreads();
    // stage tile t+1 (regs loaded last step)
    if (t + 1 < NT) {
      stageK(sKn);
      stageV(sVn);
    }
    // prefetch tile t+2 -> regs (result not needed until next step's stage)
    if (t + 2 < NT) loadTile(t + 2);

    // per-kb fused: S-quadrant -> softmax -> PV-quadrant (only ONE sacc live at a time)
#pragma unroll
    for (int kb = 0; kb < 4; ++kb) {
      // S(t) quadrant: reg r <-> kcol = kb*32 + (r&3) + 8*(r>>2) + 4h, q = l31
      f32x16 sacc = (f32x16)(0.f);
      __builtin_amdgcn_s_setprio(1);
#pragma unroll
      for (int ds = 0; ds < 8; ++ds) {
        const int r = kb * 32 + l31;
        const int p = (ds * 2 + h) ^ (r & 15);
        const half8 kf = *reinterpret_cast<const half8*>(sKc + r * 128 + p * 8);
        sacc = __builtin_amdgcn_mfma_f32_32x32x16_f16(kf, qf[ds], sacc, 0, 0, 0);
      }
      __builtin_amdgcn_s_setprio(0);

      // softmax: P = exp2(s*log2e) straight into B-frags (no cross-lane);
      // B-frag k(e) = kb16*16 + 8*(e>>2) + 4h + (e&3) == V storage order (bit2<->3 swap).
      u32 pk[8];
      float part = 0.f;
#pragma unroll
      for (int j2 = 0; j2 < 8; ++j2) {
        const float e0 = __builtin_amdgcn_exp2f(sacc[2 * j2]);
        const float e1 = __builtin_amdgcn_exp2f(sacc[2 * j2 + 1]);
        part += e0 + e1;
        half2v hp = {(_Float16)e0, (_Float16)e1};
        pk[j2] = __builtin_bit_cast(u32, hp);
      }
      lsum += part;
      u32x4 beven = {pk[0], pk[1], pk[2], pk[3]};
      u32x4 bodd = {pk[4], pk[5], pk[6], pk[7]};
      const half8 bfr0 = __builtin_bit_cast(half8, beven);
      const half8 bfr1 = __builtin_bit_cast(half8, bodd);

      // PV quadrant
      __builtin_amdgcn_s_setprio(1);
#pragma unroll
      for (int kk = 0; kk < 2; ++kk) {
        const int kb16 = kb * 2 + kk;
        const half8 bf = kk ? bfr1 : bfr0;
#pragma unroll
        for (int db = 0; db < 4; ++db) {
          const int r = db * 32 + l31;
          const int g = (kb16 * 2 + h) ^ ((r & 7) ^ ((r >> 1) & 4));
          const half8 vf = *reinterpret_cast<const half8*>(sVc + r * 128 + g * 8);
          o[db] = __builtin_amdgcn_mfma_f32_32x32x16_f16(vf, bf, o[db], 0, 0, 0);
        }
      }
      __builtin_amdgcn_s_setprio(0);
    }
  }

  // ---- epilogue ----
  // lane's lsum covers its h-half kcols; partner (xor 32) has the complement for same q.
  float inv;
  {
    float ls = lsum;
    ls += __shfl_xor(ls, 32);
    inv = 1.0f / ls;
  }

  __syncthreads();  // all waves done with K/V buffers; reuse as per-wave O-transpose buffer
  _Float16* const sO = sAll + w * 4096;  // [q 32][d 128] per wave (8KB), group-XOR swizzled

  // write O^T regs -> LDS (swizzled): q = l31, d = db*32 + grp*8 + h*4 + i
  {
    const int qrow = l31;
#pragma unroll
    for (int db = 0; db < 4; ++db)
#pragma unroll
      for (int grp = 0; grp < 4; ++grp) {
        const int d0 = db * 32 + grp * 8 + h * 4;
        half4 hv;
#pragma unroll
        for (int i = 0; i < 4; ++i) hv[i] = (_Float16)(o[db][grp * 4 + i] * inv);
        const int idx = qrow * 128 + (((d0 >> 3) ^ (qrow & 15)) << 3) + (d0 & 7);
        *reinterpret_cast<half4*>(sO + idx) = hv;
      }
  }
  // read back rows (same-wave DS ordering; sO wave-private) and store coalesced
  const int b = bh >> 3, hh = bh & 7;
#pragma unroll
  for (int it = 0; it < 8; ++it) {
    const int idx = lane + it * 64;
    const int row = idx >> 4, g = idx & 15;
    const half8 v = *reinterpret_cast<const half8*>(sO + row * 128 + ((g ^ (row & 15)) << 3));
    const size_t t = (size_t)(b * Tn + qt * 256 + w * 32 + row);
    *reinterpret_cast<half8*>(Obh + t * (HEADS * Dn) + hh * 128 + g * 8) = v;
  }
}

// ---------------- output projection, fp16 MFMA, wave-split-K ----------------
__global__ __launch_bounds__(256, 2) void outproj_kernel(const _Float16* __restrict__ Obh,
                                                         const _Float16* __restrict__ Wuh,
                                                         const float* __restrict__ bu,
                                                         float* __restrict__ out) {
  __shared__ float sR[4 * 32 * 128];
  const int tid = threadIdx.x;
  const int w = tid >> 6, lane = tid & 63, quad = lane >> 4, l16 = lane & 15;
  const int r0 = blockIdx.x * 32;

  f32x4 acc[2][8];
#pragma unroll
  for (int mt = 0; mt < 2; ++mt)
#pragma unroll
    for (int nt = 0; nt < 8; ++nt) acc[mt][nt] = (f32x4){0.f, 0.f, 0.f, 0.f};

  const _Float16* ap = Obh + (size_t)(r0 + l16) * 1024 + w * 256 + quad * 8;
  const _Float16* bp = Wuh + (size_t)l16 * 1024 + w * 256 + quad * 8;

#pragma unroll
  for (int kk = 0; kk < 8; ++kk) {
    const half8 a0 = *reinterpret_cast<const half8*>(ap + kk * 32);
    const half8 a1 = *reinterpret_cast<const half8*>(ap + 16 * 1024 + kk * 32);
#pragma unroll
    for (int nt = 0; nt < 8; ++nt) {
      const half8 bf = *reinterpret_cast<const half8*>(bp + (size_t)nt * 16 * 1024 + kk * 32);
      acc[0][nt] = __builtin_amdgcn_mfma_f32_16x16x32_f16(a0, bf, acc[0][nt], 0, 0, 0);
      acc[1][nt] = __builtin_amdgcn_mfma_f32_16x16x32_f16(a1, bf, acc[1][nt], 0, 0, 0);
    }
  }

#pragma unroll
  for (int mt = 0; mt < 2; ++mt)
#pragma unroll
    for (int nt = 0; nt < 8; ++nt)
#pragma unroll
      for (int r = 0; r < 4; ++r)
        sR[w * 4096 + (mt * 16 + quad * 4 + r) * 128 + nt * 16 + l16] = acc[mt][nt][r];
  __syncthreads();

#pragma unroll
  for (int it = 0; it < 16; ++it) {
    const int idx = tid + it * 256;
    const int row = idx >> 7, col = idx & 127;
    const float v = sR[idx] + sR[4096 + idx] + sR[8192 + idx] + sR[12288 + idx] + bu[col];
    out[(size_t)(r0 + row) * Dn + col] = v;
  }
}

}  // namespace

extern "C" void kernel_launch(void* const* d_in, const int* in_sizes, int n_in, void* d_out,
                              int out_size, void* d_ws, size_t ws_size, hipStream_t stream) {
  (void)in_sizes; (void)n_in; (void)out_size; (void)ws_size;
  const float* x = (const float*)d_in[0];
  const float* Wq = (const float*)d_in[1];
  const float* Wk = (const float*)d_in[2];
  const float* Wv = (const float*)d_in[3];
  const float* Wu = (const float*)d_in[4];
  const float* bu = (const float*)d_in[5];
  float* out = (float*)d_out;

  constexpr size_t NE = (size_t)Bn * HEADS * Tn * Dn;  // 8,388,608 elements
  char* ws = (char*)d_ws;
  _Float16* xh = (_Float16*)ws;                        // 2 MB
  _Float16* WH = (_Float16*)(ws + 2097152);            // 1 MB [Wq][Wk][Wv][Wu]
  _Float16* Qh = (_Float16*)(ws + 4194304);            // 16 MB
  _Float16* Kh = (_Float16*)(ws + 4194304 + NE * 2);   // 16 MB
  _Float16* Vt = (_Float16*)(ws + 4194304 + NE * 4);   // 16 MB
  _Float16* Obh = (_Float16*)(ws + 4194304 + NE * 6);  // 16 MB
  _Float16* Wuh = WH + 393216;

  cast_kernel<<<dim3(768), 256, 0, stream>>>(x, Wq, Wk, Wv, Wu, xh, WH);
  proj_kernel<<<dim3(64, 24), 256, 0, stream>>>(xh, WH, Qh, Kh, Vt);
  flash_kernel<<<dim3(8, 32), 512, 0, stream>>>(Qh, Kh, Vt, Obh);
  outproj_kernel<<<dim3(256), 256, 0, stream>>>(Obh, Wuh, bu, out);
}

// Round 15
// 165.745 us; speedup vs baseline: 1.1508x; 1.1508x over previous
//
#include <hip/hip_runtime.h>
#include <cmath>

namespace {

constexpr int HEADS = 8;
constexpr int Bn = 4;
constexpr int Tn = 2048;
constexpr int Dn = 128;
// Q pre-scale: 128^(-1/2) * log2(e)  (whole QK scale folded into Q, exp -> exp2)
constexpr float Q_PRESCALE = 0.1275174340f;

typedef _Float16 half8 __attribute__((ext_vector_type(8)));
typedef _Float16 half4 __attribute__((ext_vector_type(4)));
typedef _Float16 half2v __attribute__((ext_vector_type(2)));
typedef float f32x4 __attribute__((ext_vector_type(4)));
typedef float f32x16 __attribute__((ext_vector_type(16)));
typedef unsigned int u32;
typedef unsigned int u32x4 __attribute__((ext_vector_type(4)));

// ---------------- cast inputs to fp16 ----------------
// (R10 lesson: fusing the cast into proj/outproj regressed ~+30us — f32 operand streams
// double L2/L3 traffic. Keep the separate cast kernel.)
__global__ __launch_bounds__(256) void cast_kernel(
    const float* __restrict__ x, const float* __restrict__ Wq, const float* __restrict__ Wk,
    const float* __restrict__ Wv, const float* __restrict__ Wu, _Float16* __restrict__ xh,
    _Float16* __restrict__ WH) {
  const int idx = blockIdx.x * 256 + threadIdx.x;
  const size_t base = (size_t)idx * 8;
  const float* src;
  _Float16* dst;
  if (base < 1048576) {
    src = x + base;
    dst = xh + base;
  } else {
    const size_t r = base - 1048576;
    const int s = (int)(r >> 17);
    src = ((s == 0) ? Wq : (s == 1) ? Wk : (s == 2) ? Wv : Wu) + (r & 131071);
    dst = WH + r;
  }
  const float4 a = *reinterpret_cast<const float4*>(src);
  const float4 b = *reinterpret_cast<const float4*>(src + 4);
  half8 h;
  h[0] = (_Float16)a.x; h[1] = (_Float16)a.y; h[2] = (_Float16)a.z; h[3] = (_Float16)a.w;
  h[4] = (_Float16)b.x; h[5] = (_Float16)b.y; h[6] = (_Float16)b.z; h[7] = (_Float16)b.w;
  *reinterpret_cast<half8*>(dst) = h;
}

// ---------------- QKV projection, fp16 MFMA ----------------
// Qh gets Q_PRESCALE folded (so flash S-MFMA output is s*log2e); Kh/Vt unscaled.
__global__ __launch_bounds__(256, 4) void proj_kernel(const _Float16* __restrict__ xh,
                                                      const _Float16* __restrict__ WH,
                                                      _Float16* __restrict__ Qh,
                                                      _Float16* __restrict__ Kh,
                                                      _Float16* __restrict__ Vt) {
  __shared__ _Float16 sB[128 * 136];
  const int tid = threadIdx.x;
  const int w = tid >> 6, lane = tid & 63, quad = lane >> 4, l16 = lane & 15;
  const int m0 = blockIdx.x * 128;
  const int n0 = blockIdx.y * 128;

#pragma unroll
  for (int it = 0; it < 8; ++it) {
    const int fid = tid + it * 256;
    const int r = fid >> 4, g = fid & 15;
    const half8 v = *reinterpret_cast<const half8*>(WH + (size_t)(n0 + r) * 128 + g * 8);
    const int p = g ^ (r & 15);
    *reinterpret_cast<half8*>(sB + r * 128 + p * 8) = v;
  }

  half8 af[2][4];
  const _Float16* xp = xh + (size_t)(m0 + w * 32 + l16) * 128 + quad * 8;
#pragma unroll
  for (int mt = 0; mt < 2; ++mt)
#pragma unroll
    for (int kk = 0; kk < 4; ++kk)
      af[mt][kk] = *reinterpret_cast<const half8*>(xp + mt * 16 * 128 + kk * 32);

  __syncthreads();

  f32x4 acc[2][8];
#pragma unroll
  for (int mt = 0; mt < 2; ++mt)
#pragma unroll
    for (int nt = 0; nt < 8; ++nt) acc[mt][nt] = (f32x4){0.f, 0.f, 0.f, 0.f};

#pragma unroll
  for (int kk = 0; kk < 4; ++kk)
#pragma unroll
    for (int nt = 0; nt < 8; ++nt) {
      const int r = nt * 16 + l16;
      const int p = (kk * 4 + quad) ^ l16;
      const half8 bf = *reinterpret_cast<const half8*>(sB + r * 128 + p * 8);
      acc[0][nt] = __builtin_amdgcn_mfma_f32_16x16x32_f16(af[0][kk], bf, acc[0][nt], 0, 0, 0);
      acc[1][nt] = __builtin_amdgcn_mfma_f32_16x16x32_f16(af[1][kk], bf, acc[1][nt], 0, 0, 0);
    }

  const int sel = n0 >> 10;
  const int h = (n0 >> 7) & 7;
  const int b = m0 >> 11;
  const int t0b = m0 & 2047;
  const int bh = b * HEADS + h;
  const float scale = (sel == 0) ? Q_PRESCALE : 1.0f;

  __syncthreads();

  if (sel < 2) {
#pragma unroll
    for (int mt = 0; mt < 2; ++mt)
#pragma unroll
      for (int nt = 0; nt < 8; ++nt)
#pragma unroll
        for (int r = 0; r < 4; ++r)
          sB[(w * 32 + mt * 16 + quad * 4 + r) * 136 + nt * 16 + l16] =
              (_Float16)(acc[mt][nt][r] * scale);
  } else {
#pragma unroll
    for (int mt = 0; mt < 2; ++mt)
#pragma unroll
      for (int nt = 0; nt < 8; ++nt)
#pragma unroll
        for (int r = 0; r < 4; ++r)
          sB[(nt * 16 + l16) * 136 + w * 32 + mt * 16 + quad * 4 + r] = (_Float16)acc[mt][nt][r];
  }
  __syncthreads();

  _Float16* dstbase;
  size_t rstride;
  if (sel == 0) {
    dstbase = Qh + ((size_t)bh * Tn + t0b) * Dn;
    rstride = Dn;
  } else if (sel == 1) {
    dstbase = Kh + ((size_t)bh * Tn + t0b) * Dn;
    rstride = Dn;
  } else {
    dstbase = Vt + ((size_t)bh * Dn) * Tn + t0b;
    rstride = Tn;
  }
#pragma unroll
  for (int it = 0; it < 8; ++it) {
    const int fid = tid + it * 256;
    const int r = fid >> 4, g = fid & 15;
    const half8 v = *reinterpret_cast<const half8*>(sB + r * 136 + g * 8);
    *reinterpret_cast<half8*>(dstbase + (size_t)r * rstride + g * 8) = v;
  }
}

// ---------------- fp16 MFMA flash attention (TLP: 8 waves share one K/V copy) ----------------
// R7 verified: 32 q/wave, 8 waves/block (2/SIMD), one barrier/step, K dbuf + V tbuf,
// V column-permuted store (bit2<->3) so P stays in registers. 74.4us, MfmaUtil 41.
// R10 verified: XCD-aware block remap (4 bh x 8 qt per XCD -> K/V XCD-L2-resident,
// FETCH_SIZE 139 -> 24.6 MB) + s_setprio(1) around MFMA clusters. 73.5us, MfmaUtil 40.
// R12/R14 falsified: KT=128 single-barrier variants spill (WRITE_SIZE 43-56MB scratch,
// MfmaUtil 24-27) regardless of sacc consumption order — KT=64 with 16-reg staging is
// the regime that fits the 2-waves/SIMD register budget. This is the session-best flash.
__global__ __launch_bounds__(512, 2) void flash_kernel(const _Float16* __restrict__ Qh,
                                                       const _Float16* __restrict__ Kh,
                                                       const _Float16* __restrict__ Vt,
                                                       _Float16* __restrict__ Obh) {
  __shared__ _Float16 sAll[40960];
  // kbuf b: sAll + b*8192           [kcol 64][d 128], group p = g ^ (kcol&15)
  // vbuf v: sAll + 16384 + v*8192   [d 128][col 64],  group p = g ^ ((d&7)^((d>>1)&4)),
  //         storage col s holds key t = swapbits23(s)

  const int tid = threadIdx.x;
  const int w = tid >> 6;      // 0..7
  const int lane = tid & 63;
  const int l31 = lane & 31;
  const int h = lane >> 5;     // lane half
  // XCD-aware remap (bijective over 256 blocks): dispatch id lid round-robins XCDs
  // (xcd = lid&7); give XCD x the blocks for bh in [4x, 4x+4) so K/V is XCD-L2-resident.
  const int lid = blockIdx.x + 8 * blockIdx.y;  // 0..255
  const int xcd = lid & 7, j = lid >> 3;        // j 0..31
  const int bh = xcd * 4 + (j >> 3);            // 0..31
  const int qt = j & 7;                         // 0..7
  constexpr int NT = Tn / 64;  // 32 steps

  // Q fragments (B-operand, 32x32x16): lane holds Q[q = qt*256 + w*32 + l31][ds*16+h*8+e]
  half8 qf[8];
  {
    const _Float16* Qp = Qh + ((size_t)bh * Tn + qt * 256 + w * 32 + l31) * Dn + h * 8;
#pragma unroll
    for (int ds = 0; ds < 8; ++ds) qf[ds] = *reinterpret_cast<const half8*>(Qp + ds * 16);
  }

  const _Float16* Kp = Kh + (size_t)bh * Tn * Dn;
  const _Float16* Vp = Vt + (size_t)bh * Dn * Tn;

  // O^T accumulators: o[db], D[row = d][col = q] (32x32 C-layout)
  f32x16 o[4];
#pragma unroll
  for (int db = 0; db < 4; ++db) o[db] = (f32x16)(0.f);
  float lsum = 0.f;

  // staging (512 threads): K rows kr, kr+32; V rows vr, vr+64
  half8 kreg[2], vreg[2];
  const int kr = tid >> 4, kg = tid & 15;   // kr 0..31
  const int vr = tid >> 3, vg = tid & 7;    // vr 0..63
  // V column-permuted store (bit2<->bit3 of key index; self-inverse within-16)
  const int vG = (vg >> 1) * 2;
  const int vO = (vg & 1) * 4;

  // ---- prologue: tile 0 -> kbuf0/vbuf0, load tile 1 regs, barrier, S(0) -> scA ----
#pragma unroll
  for (int it = 0; it < 2; ++it) {
    kreg[it] = *reinterpret_cast<const half8*>(Kp + (size_t)(kr + it * 32) * Dn + kg * 8);
    vreg[it] = *reinterpret_cast<const half8*>(Vp + (size_t)(vr + it * 64) * Tn + vg * 8);
  }
  {
    _Float16* sK0 = sAll;
    _Float16* sV0 = sAll + 16384;
#pragma unroll
    for (int it = 0; it < 2; ++it) {
      const int r = kr + it * 32;
      const int p = kg ^ (r & 15);
      *reinterpret_cast<half8*>(sK0 + r * 128 + p * 8) = kreg[it];
      const int rv = vr + it * 64;
      const int sw = (rv & 7) ^ ((rv >> 1) & 4);
      const half8 v = vreg[it];
      half4 lo, hi;
      lo[0] = v[0]; lo[1] = v[1]; lo[2] = v[2]; lo[3] = v[3];
      hi[0] = v[4]; hi[1] = v[5]; hi[2] = v[6]; hi[3] = v[7];
      *reinterpret_cast<half4*>(sV0 + rv * 64 + ((vG ^ sw) * 8) + vO) = lo;
      *reinterpret_cast<half4*>(sV0 + rv * 64 + (((vG + 1) ^ sw) * 8) + vO) = hi;
    }
  }
#pragma unroll
  for (int it = 0; it < 2; ++it) {
    kreg[it] = *reinterpret_cast<const half8*>(Kp + (size_t)(64 + kr + it * 32) * Dn + kg * 8);
    vreg[it] = *reinterpret_cast<const half8*>(Vp + (size_t)(vr + it * 64) * Tn + 64 + vg * 8);
  }
  __syncthreads();

  // S^T(0) into scA: sacc[kb]; reg r <-> kcol = kb*32 + (r&3) + 8*(r>>2) + 4h, q = l31
  f32x16 scA[2], scB[2];
  scA[0] = (f32x16)(0.f);
  scA[1] = (f32x16)(0.f);
#pragma unroll
  for (int ds = 0; ds < 8; ++ds) {
    const int p = (ds * 2 + h) ^ (l31 & 15);
    const half8 kf0 = *reinterpret_cast<const half8*>(sAll + l31 * 128 + p * 8);
    const half8 kf1 = *reinterpret_cast<const half8*>(sAll + (32 + l31) * 128 + p * 8);
    scA[0] = __builtin_amdgcn_mfma_f32_32x32x16_f16(kf0, qf[ds], scA[0], 0, 0, 0);
    scA[1] = __builtin_amdgcn_mfma_f32_32x32x16_f16(kf1, qf[ds], scA[1], 0, 0, 0);
  }

  // ---- main loop: step(t) consumes sc (=S(t)), produces sn (=S(t+1)) ----
  auto step = [&](int t, f32x16 (&sc)[2], f32x16 (&sn)[2]) {
    _Float16* sKn = sAll + ((t + 1) & 1) * 8192;
    _Float16* sVc = sAll + 16384 + (t % 3) * 8192;
    _Float16* sVn = sAll + 16384 + ((t + 1) % 3) * 8192;

    // ph1: stage tile t+1 (regs prefetched last step)
    if (t + 1 < NT) {
#pragma unroll
      for (int it = 0; it < 2; ++it) {
        const int r = kr + it * 32;
        const int p = kg ^ (r & 15);
        *reinterpret_cast<half8*>(sKn + r * 128 + p * 8) = kreg[it];
        const int rv = vr + it * 64;
        const int sw = (rv & 7) ^ ((rv >> 1) & 4);
        const half8 v = vreg[it];
        half4 lo, hi;
        lo[0] = v[0]; lo[1] = v[1]; lo[2] = v[2]; lo[3] = v[3];
        hi[0] = v[4]; hi[1] = v[5]; hi[2] = v[6]; hi[3] = v[7];
        *reinterpret_cast<half4*>(sVn + rv * 64 + ((vG ^ sw) * 8) + vO) = lo;
        *reinterpret_cast<half4*>(sVn + rv * 64 + (((vG + 1) ^ sw) * 8) + vO) = hi;
      }
    }
    __syncthreads();
    // prefetch tile t+2 -> regs (hides under compute)
    if (t + 2 < NT) {
      const _Float16* knext = Kp + (size_t)(t + 2) * 64 * Dn;
      const _Float16* vnext = Vp + (t + 2) * 64;
#pragma unroll
      for (int it = 0; it < 2; ++it) {
        kreg[it] = *reinterpret_cast<const half8*>(knext + (size_t)(kr + it * 32) * Dn + kg * 8);
        vreg[it] = *reinterpret_cast<const half8*>(vnext + (size_t)(vr + it * 64) * Tn + vg * 8);
      }
    }

    if (t + 1 < NT) {
      sn[0] = (f32x16)(0.f);
      sn[1] = (f32x16)(0.f);
    }

    // fused phase: softmax-half(t) | S-slices(t+1) | PV-slices(t)
    half8 bfr[4];
#pragma unroll
    for (int i = 0; i < 2; ++i) {
      const int kb = i;
      // softmax half: P = exp2(s*log2e) straight into B-frag regs (no cross-lane)
      {
        u32 pk[8];
        float part = 0.f;
#pragma unroll
        for (int j2 = 0; j2 < 8; ++j2) {
          const float e0 = __builtin_amdgcn_exp2f(sc[kb][2 * j2]);
          const float e1 = __builtin_amdgcn_exp2f(sc[kb][2 * j2 + 1]);
          part += e0 + e1;
          half2v hp = {(_Float16)e0, (_Float16)e1};
          pk[j2] = __builtin_bit_cast(u32, hp);
        }
        lsum += part;
        u32x4 beven = {pk[0], pk[1], pk[2], pk[3]};
        u32x4 bodd = {pk[4], pk[5], pk[6], pk[7]};
        bfr[kb * 2] = __builtin_bit_cast(half8, beven);
        bfr[kb * 2 + 1] = __builtin_bit_cast(half8, bodd);
      }
      // S(t+1) slices ds = 4i .. 4i+3 (independent of sm/PV)
      if (t + 1 < NT) {
        __builtin_amdgcn_s_setprio(1);
#pragma unroll
        for (int dd = 0; dd < 4; ++dd) {
          const int ds = 4 * i + dd;
          const int p = (ds * 2 + h) ^ (l31 & 15);
          const half8 kf0 = *reinterpret_cast<const half8*>(sKn + l31 * 128 + p * 8);
          const half8 kf1 = *reinterpret_cast<const half8*>(sKn + (32 + l31) * 128 + p * 8);
          sn[0] = __builtin_amdgcn_mfma_f32_32x32x16_f16(kf0, qf[ds], sn[0], 0, 0, 0);
          sn[1] = __builtin_amdgcn_mfma_f32_32x32x16_f16(kf1, qf[ds], sn[1], 0, 0, 0);
        }
        __builtin_amdgcn_s_setprio(0);
      }
      // PV slices kb16 = 2i-2, 2i-1 (bfr ready from previous half)
      if (i >= 1) {
        __builtin_amdgcn_s_setprio(1);
#pragma unroll
        for (int kk = 0; kk < 2; ++kk) {
          const int kb16 = kk;
#pragma unroll
          for (int db = 0; db < 4; ++db) {
            const int r = db * 32 + l31;
            const int pv = (kb16 * 2 + h) ^ ((r & 7) ^ ((r >> 1) & 4));
            const half8 vf = *reinterpret_cast<const half8*>(sVc + r * 64 + pv * 8);
            o[db] = __builtin_amdgcn_mfma_f32_32x32x16_f16(vf, bfr[kb16], o[db], 0, 0, 0);
          }
        }
        __builtin_amdgcn_s_setprio(0);
      }
    }
    // tail PV slices kb16 = 2, 3
    __builtin_amdgcn_s_setprio(1);
#pragma unroll
    for (int kk = 2; kk < 4; ++kk) {
      const int kb16 = kk;
#pragma unroll
      for (int db = 0; db < 4; ++db) {
        const int r = db * 32 + l31;
        const int pv = (kb16 * 2 + h) ^ ((r & 7) ^ ((r >> 1) & 4));
        const half8 vf = *reinterpret_cast<const half8*>(sVc + r * 64 + pv * 8);
        o[db] = __builtin_amdgcn_mfma_f32_32x32x16_f16(vf, bfr[kb16], o[db], 0, 0, 0);
      }
    }
    __builtin_amdgcn_s_setprio(0);
  };

  for (int st = 0; st < NT; st += 2) {
    step(st, scA, scB);
    step(st + 1, scB, scA);
  }

  // ---- epilogue ----
  // lane's lsum covers its h-half kcols; partner (xor 32) has the complement for same q.
  float inv;
  {
    float ls = lsum;
    ls += __shfl_xor(ls, 32);
    inv = 1.0f / ls;
  }

  __syncthreads();  // all waves done with K/V buffers; reuse as per-wave O-transpose buffer
  _Float16* const sO = sAll + w * 4096;  // [q 32][d 128] per wave (8KB), group-XOR swizzled

  // write O^T regs -> LDS (swizzled): q = l31, d = db*32 + grp*8 + h*4 + i
  {
    const int qrow = l31;
#pragma unroll
    for (int db = 0; db < 4; ++db)
#pragma unroll
      for (int grp = 0; grp < 4; ++grp) {
        const int d0 = db * 32 + grp * 8 + h * 4;
        half4 hv;
#pragma unroll
        for (int i = 0; i < 4; ++i) hv[i] = (_Float16)(o[db][grp * 4 + i] * inv);
        const int idx = qrow * 128 + (((d0 >> 3) ^ (qrow & 15)) << 3) + (d0 & 7);
        *reinterpret_cast<half4*>(sO + idx) = hv;
      }
  }
  // read back rows (same-wave DS ordering; sO wave-private) and store coalesced
  const int b = bh >> 3, hh = bh & 7;
#pragma unroll
  for (int it = 0; it < 8; ++it) {
    const int idx = lane + it * 64;
    const int row = idx >> 4, g = idx & 15;
    const half8 v = *reinterpret_cast<const half8*>(sO + row * 128 + ((g ^ (row & 15)) << 3));
    const size_t t = (size_t)(b * Tn + qt * 256 + w * 32 + row);
    *reinterpret_cast<half8*>(Obh + t * (HEADS * Dn) + hh * 128 + g * 8) = v;
  }
}

// ---------------- output projection, fp16 MFMA, wave-split-K ----------------
__global__ __launch_bounds__(256, 2) void outproj_kernel(const _Float16* __restrict__ Obh,
                                                         const _Float16* __restrict__ Wuh,
                                                         const float* __restrict__ bu,
                                                         float* __restrict__ out) {
  __shared__ float sR[4 * 32 * 128];
  const int tid = threadIdx.x;
  const int w = tid >> 6, lane = tid & 63, quad = lane >> 4, l16 = lane & 15;
  const int r0 = blockIdx.x * 32;

  f32x4 acc[2][8];
#pragma unroll
  for (int mt = 0; mt < 2; ++mt)
#pragma unroll
    for (int nt = 0; nt < 8; ++nt) acc[mt][nt] = (f32x4){0.f, 0.f, 0.f, 0.f};

  const _Float16* ap = Obh + (size_t)(r0 + l16) * 1024 + w * 256 + quad * 8;
  const _Float16* bp = Wuh + (size_t)l16 * 1024 + w * 256 + quad * 8;

#pragma unroll
  for (int kk = 0; kk < 8; ++kk) {
    const half8 a0 = *reinterpret_cast<const half8*>(ap + kk * 32);
    const half8 a1 = *reinterpret_cast<const half8*>(ap + 16 * 1024 + kk * 32);
#pragma unroll
    for (int nt = 0; nt < 8; ++nt) {
      const half8 bf = *reinterpret_cast<const half8*>(bp + (size_t)nt * 16 * 1024 + kk * 32);
      acc[0][nt] = __builtin_amdgcn_mfma_f32_16x16x32_f16(a0, bf, acc[0][nt], 0, 0, 0);
      acc[1][nt] = __builtin_amdgcn_mfma_f32_16x16x32_f16(a1, bf, acc[1][nt], 0, 0, 0);
    }
  }

#pragma unroll
  for (int mt = 0; mt < 2; ++mt)
#pragma unroll
    for (int nt = 0; nt < 8; ++nt)
#pragma unroll
      for (int r = 0; r < 4; ++r)
        sR[w * 4096 + (mt * 16 + quad * 4 + r) * 128 + nt * 16 + l16] = acc[mt][nt][r];
  __syncthreads();

#pragma unroll
  for (int it = 0; it < 16; ++it) {
    const int idx = tid + it * 256;
    const int row = idx >> 7, col = idx & 127;
    const float v = sR[idx] + sR[4096 + idx] + sR[8192 + idx] + sR[12288 + idx] + bu[col];
    out[(size_t)(r0 + row) * Dn + col] = v;
  }
}

}  // namespace

extern "C" void kernel_launch(void* const* d_in, const int* in_sizes, int n_in, void* d_out,
                              int out_size, void* d_ws, size_t ws_size, hipStream_t stream) {
  (void)in_sizes; (void)n_in; (void)out_size; (void)ws_size;
  const float* x = (const float*)d_in[0];
  const float* Wq = (const float*)d_in[1];
  const float* Wk = (const float*)d_in[2];
  const float* Wv = (const float*)d_in[3];
  const float* Wu = (const float*)d_in[4];
  const float* bu = (const float*)d_in[5];
  float* out = (float*)d_out;

  constexpr size_t NE = (size_t)Bn * HEADS * Tn * Dn;  // 8,388,608 elements
  char* ws = (char*)d_ws;
  _Float16* xh = (_Float16*)ws;                        // 2 MB
  _Float16* WH = (_Float16*)(ws + 2097152);            // 1 MB [Wq][Wk][Wv][Wu]
  _Float16* Qh = (_Float16*)(ws + 4194304);            // 16 MB
  _Float16* Kh = (_Float16*)(ws + 4194304 + NE * 2);   // 16 MB
  _Float16* Vt = (_Float16*)(ws + 4194304 + NE * 4);   // 16 MB
  _Float16* Obh = (_Float16*)(ws + 4194304 + NE * 6);  // 16 MB
  _Float16* Wuh = WH + 393216;

  cast_kernel<<<dim3(768), 256, 0, stream>>>(x, Wq, Wk, Wv, Wu, xh, WH);
  proj_kernel<<<dim3(64, 24), 256, 0, stream>>>(xh, WH, Qh, Kh, Vt);
  flash_kernel<<<dim3(8, 32), 512, 0, stream>>>(Qh, Kh, Vt, Obh);
  outproj_kernel<<<dim3(256), 256, 0, stream>>>(Obh, Wuh, bu, out);
}